// Round 10
// baseline (505.100 us; speedup 1.0000x reference)
//
#include <hip/hip_runtime.h>

// RuleFilter: out[0] = logits[0]; out[i] = logits[i] * mask_table[argmax(out[i-1])]
// logits: (L=128, N=4096, V=128) fp32, mask_table: (V,V) fp32 {0,1}.
//
// R10: LDS-relay wave specialization. Measured law R0-R9: a chained wave
// completes ~1 load-step per 1.2-1.4us regardless of depth/width/occupancy;
// hypothesis: the wall is ADDITIVE (memory wait + ~0.2us of serial VALU
// argmax/publish between waits). Test: strip ALL chain VALU off the
// streaming wave. Per block (1 sequence): wave0 CONSUMER streams rows
// (asm ring, R9's exact vmcnt ledger), relays raw rows to LDS, masks with
// the producer-supplied prev, stores. wave1 PRODUCER (zero HBM ops) reads
// rows from LDS, masks+argmaxes, publishes prev(i+1) as a self-contained
// flag word (0x100|prev). HBM traffic optimal: 268MB read + 268MB write.
// Protocol: flag_r[i] guards LDS row data (lgkmcnt fence before set);
// flag_p[] carries its payload in the flag word (no fence needed).
// Deadlock-free: producer lags consumer <=2 rows; 4 LDS slots.

constexpr int V = 128;
constexpr int L = 128;
constexpr int N = 4096;
constexpr int D  = 15;   // rows in flight (consumer)
constexpr int RD = 16;   // ring slots
constexpr unsigned ROWB = (unsigned)N * V * 4;  // 2 MiB between rows

typedef __attribute__((ext_vector_type(2))) float f32x2;
typedef unsigned long long u64;

// Full 64-lane max, broadcast (HW-verified R0-R9).
__device__ __forceinline__ float wave_max_dpp(float x) {
    int v = __float_as_int(x);
    const int ninf = __float_as_int(-__builtin_inff());
#define RF_STEP(ctrl)                                                          \
    {                                                                          \
        int s = __builtin_amdgcn_update_dpp(ninf, v, ctrl, 0xf, 0xf, false);   \
        v = __float_as_int(fmaxf(__int_as_float(v), __int_as_float(s)));       \
    }
    RF_STEP(0x111) RF_STEP(0x112) RF_STEP(0x114) RF_STEP(0x118)
    RF_STEP(0x142) RF_STEP(0x143)
#undef RF_STEP
    return __int_as_float(__builtin_amdgcn_readlane(v, 63));
}

// argmax over {f.x@2*lane, f.y@2*lane+1}; ties -> lowest index (HW-verified).
__device__ __forceinline__ int wave_argmax(f32x2 f) {
    const float bv = wave_max_dpp(fmaxf(f.x, f.y));
    u64 b0 = __ballot(f.x == bv);
    u64 b1 = __ballot(f.y == bv);
    int i0 = __ffsll(b0), i1 = __ffsll(b1);
    int c0 = i0 ? (i0 - 1) * 2 : (1 << 30);
    int c1 = i1 ? (i1 - 1) * 2 + 1 : (1 << 30);
    return min(c0, c1);
}

__device__ __forceinline__ unsigned sel8(const unsigned* t, int j) {
    unsigned a0 = (j & 1) ? t[1] : t[0];
    unsigned a1 = (j & 1) ? t[3] : t[2];
    unsigned a2 = (j & 1) ? t[5] : t[4];
    unsigned a3 = (j & 1) ? t[7] : t[6];
    unsigned b0 = (j & 2) ? a1 : a0;
    unsigned b1 = (j & 2) ? a3 : a2;
    return (j & 4) ? b1 : b0;
}

__device__ __forceinline__ u64 uniform_u64(const void* p) {
    u64 x = (u64)p;
    unsigned lo = __builtin_amdgcn_readfirstlane((unsigned)x);
    unsigned hi = __builtin_amdgcn_readfirstlane((unsigned)(x >> 32));
    return ((u64)hi << 32) | lo;
}

// Consumer step at ring phase J; absolute row I = irow + J.
// PH: 0=prologue,1=steady,2=epilogue. Exact vmcnt ledger (R9-proven):
// pro: 15+J; steady: 30; epi J>0: 30-J. Never 0 mid-stream.
template <int PH, int J>
struct CWalk {
    static constexpr int  NW    = (PH == 0) ? (15 + J)
                                 : ((PH == 2 && J > 0) ? (30 - J) : 30);
    static constexpr bool PF    = (PH != 2) || (J == 0);
    static constexpr bool FIRST = (PH == 0 && J == 0);
    static constexpr int  rs    = J & 15;
    static constexpr int  ps    = (J + D) & 15;

    static __device__ __forceinline__ void run(f32x2* ring, const unsigned* tbl,
                                               int irow, unsigned ibase,
                                               u64 lbase, u64 obase,
                                               float* rowbuf,
                                               volatile unsigned* flag_r,
                                               volatile unsigned* flag_p,
                                               int lane) {
        if constexpr (PF) {
            unsigned voff = ibase + (unsigned)(J + D) * ROWB;
            asm volatile("global_load_dwordx2 %0, %1, %2"
                         : "=&v"(ring[ps])
                         : "v"(voff), "s"(lbase));
        }

        asm volatile("s_waitcnt vmcnt(%c1)" : "+v"(ring[rs]) : "i"(NW));
        f32x2 c = ring[rs];

        // Relay raw row to the producer: data -> LDS-fence -> flag.
        *(f32x2*)&rowbuf[((irow + J) & 3) * V + lane * 2] = c;
        asm volatile("s_waitcnt lgkmcnt(0)" ::: "memory");
        if (lane == 0) flag_r[irow + J] = 1u;

        f32x2 f;
        if constexpr (FIRST) {
            f = c;  // row 0 unfiltered
        } else {
            unsigned v;
            while (((v = flag_p[irow + J]) & 0x100u) == 0u) {}  // usually ready
            int pv = (int)(v & 127u);
            unsigned word = sel8(tbl, pv >> 4);
            unsigned fb   = (word >> ((pv & 15) * 2)) & 3u;
            f.x = (fb & 1u) ? c.x : 0.0f;
            f.y = (fb & 2u) ? c.y : 0.0f;
        }
        ring[rs] = f;  // in-place store data (ledger proves WAR-safe)
        {
            unsigned voff = ibase + (unsigned)J * ROWB;
            asm volatile("global_store_dwordx2 %0, %1, %2"
                         :: "v"(voff), "v"(ring[rs]), "s"(obase));
        }

        CWalk<PH, J + 1>::run(ring, tbl, irow, ibase, lbase, obase, rowbuf,
                              flag_r, flag_p, lane);
    }
};
template <int PH>
struct CWalk<PH, 16> {
    static __device__ __forceinline__ void run(f32x2*, const unsigned*, int,
                                               unsigned, u64, u64, float*,
                                               volatile unsigned*,
                                               volatile unsigned*, int) {}
};

__global__ __launch_bounds__(128, 8) void rule_filter_kernel(
    const float* __restrict__ logits,      // (L, N, V)
    const float* __restrict__ mask_table,  // (V, V)
    float* __restrict__ out)               // (L, N, V)
{
    __shared__ float    rowbuf[4 * V];   // 4-slot raw-row relay (2 KiB)
    __shared__ unsigned flagr[L];        // row i data committed
    __shared__ unsigned flagp[L];        // 0x100 | prev(i)

    const int w    = threadIdx.x >> 6;  // 0 = consumer, 1 = producer
    const int lane = threadIdx.x & 63;
    const int n    = blockIdx.x;        // sequence

    const u64 lbase = uniform_u64(logits + (size_t)n * V);
    const u64 obase = uniform_u64(out    + (size_t)n * V);
    const unsigned laneoff = (unsigned)lane * 8;  // dwordx2 per lane

    // Per-lane mask table (both waves need it):
    // tbl[j] bits(2r..2r+1) = mask_table[16j+r][2*lane .. 2*lane+1]
    unsigned tbl[8];
#pragma unroll 1
    for (int j = 0; j < 8; ++j) {
        unsigned acc = 0;
#pragma unroll
        for (int r = 0; r < 16; ++r) {
            const int p = j * 16 + r;
            float2 mv = *(const float2*)(mask_table + (size_t)p * V + lane * 2);
            acc |= ((mv.x != 0.0f ? 1u : 0u) | (mv.y != 0.0f ? 2u : 0u)) << (2 * r);
        }
        tbl[j] = acc;
    }

    flagr[threadIdx.x] = 0;
    flagp[threadIdx.x] = 0;
    __syncthreads();  // drains all counters -> exact ledger baseline

    volatile unsigned* flag_r = flagr;
    volatile unsigned* flag_p = flagp;

    if (w == 0) {
        // ---------------- consumer: sole HBM streamer ----------------
        f32x2 ring[RD];
#pragma unroll
        for (int r = 0; r < D; ++r) {
            unsigned voff = (unsigned)r * ROWB + laneoff;
            asm volatile("global_load_dwordx2 %0, %1, %2"
                         : "=&v"(ring[r])
                         : "v"(voff), "s"(lbase));
        }
        int irow = 0;
        unsigned ibase = laneoff;
        CWalk<0, 0>::run(ring, tbl, irow, ibase, lbase, obase, rowbuf,
                         flag_r, flag_p, lane);
        irow = 16; ibase += 16u * ROWB;
#pragma unroll 1
        for (int m = 0; m < 6; ++m) {
            CWalk<1, 0>::run(ring, tbl, irow, ibase, lbase, obase, rowbuf,
                             flag_r, flag_p, lane);
            irow += 16; ibase += 16u * ROWB;
        }
        CWalk<2, 0>::run(ring, tbl, irow, ibase, lbase, obase, rowbuf,
                         flag_r, flag_p, lane);
        asm volatile("s_waitcnt vmcnt(0)" ::: "memory");  // drain asm stores
    } else {
        // ---------------- producer: zero HBM, runs the chain ----------------
        int prev = 0;
#pragma unroll 1
        for (int i = 0; i < L - 1; ++i) {
            while (flag_r[i] == 0u) {}
            asm volatile("" ::: "memory");  // no hoisting data read above spin
            f32x2 c = *(f32x2*)&rowbuf[(i & 3) * V + lane * 2];
            f32x2 f;
            if (i == 0) {
                f = c;  // row 0 unfiltered
            } else {
                unsigned word = sel8(tbl, prev >> 4);
                unsigned fb   = (word >> ((prev & 15) * 2)) & 3u;
                f.x = (fb & 1u) ? c.x : 0.0f;
                f.y = (fb & 2u) ? c.y : 0.0f;
            }
            prev = wave_argmax(f);
            if (lane == 0) flag_p[i + 1] = 0x100u | (unsigned)prev;
        }
    }
}

extern "C" void kernel_launch(void* const* d_in, const int* in_sizes, int n_in,
                              void* d_out, int out_size, void* d_ws, size_t ws_size,
                              hipStream_t stream) {
    const float* logits     = (const float*)d_in[0];  // (L, N, V) fp32
    const float* mask_table = (const float*)d_in[1];  // (V, V) fp32
    float* out              = (float*)d_out;          // (L, N, V) fp32

    dim3 grid(N);      // one block (consumer+producer wave) per sequence
    dim3 block(128);
    rule_filter_kernel<<<grid, block, 0, stream>>>(logits, mask_table, out);
}

// Round 11
// 437.741 us; speedup vs baseline: 1.1539x; 1.1539x over previous
//
#include <hip/hip_runtime.h>

// RuleFilter: out[0] = logits[0]; out[i] = logits[i] * mask_table[argmax(out[i-1])]
// logits: (L=128, N=4096, V=128) fp32, mask_table: (128,128) fp32 {0,1}.
// One wave per sequence n; lane holds vocab elems {2*lane, 2*lane+1}.
//
// FINAL (R11 = R4 restored): best verified configuration of this session.
// Measured session law (R0-R10): a streaming wave on MI355X delivers
// ~0.8-0.86 GB/s r+w regardless of ring depth (8-20), op width (256B-1KB),
// occupancy (16-32 waves/CU), or nt/no-nt; total BW = productive waves x
// that rate. This problem has exactly 4096 independent chains; structures
// that add helper waves per chain (vocab-split lockstep R8, decoupled dual
// stream R9, LDS relay R10, 4-kernel decomposition R7) all lose more to
// coordination (barrier jitter / spin / bank conflicts / double traffic)
// than they gain. 4096 waves x 0.86 GB/s = 3.5 TB/s logical over 537 MB
// -> ~152 us dispatch: this kernel sits on that line.
//
// Structure: all-asm vmem pipeline (invisible to the backend's conservative
// waitcnt insertion), register ring D=20, exact per-step s_waitcnt vmcnt(N)
// (steady N=2D-2=38, never 0), plain (L2-acking) stores, ordering enforced
// by register ties rather than "memory" clobbers.

constexpr int V = 128;
constexpr int L = 128;
constexpr int N = 4096;
constexpr int D = 20;  // register ring depth (rows in flight); % D is constexpr
constexpr unsigned ROWB = (unsigned)N * V * 4;  // 2 MiB: byte stride between rows

typedef __attribute__((ext_vector_type(2))) float f32x2;

// Wave-wide max of x (all 64 lanes active), result broadcast to all lanes.
__device__ __forceinline__ float wave_max_dpp(float x) {
    int v = __float_as_int(x);
    const int ninf = __float_as_int(-__builtin_inff());
#define RF_STEP(ctrl)                                                          \
    {                                                                          \
        int s = __builtin_amdgcn_update_dpp(ninf, v, ctrl, 0xf, 0xf, false);   \
        v = __float_as_int(fmaxf(__int_as_float(v), __int_as_float(s)));       \
    }
    RF_STEP(0x111)  // row_shr:1
    RF_STEP(0x112)  // row_shr:2
    RF_STEP(0x114)  // row_shr:4
    RF_STEP(0x118)  // row_shr:8  -> lane 15 of each row16 has row max
    RF_STEP(0x142)  // row_bcast:15 -> lane31 = max(0..31), lane63 = max(32..63)
    RF_STEP(0x143)  // row_bcast:31 -> lane63 = max(all)
#undef RF_STEP
    return __int_as_float(__builtin_amdgcn_readlane(v, 63));
}

// argmax over the 128 values {f.x@2*lane, f.y@2*lane+1}; ties -> lowest index.
__device__ __forceinline__ int wave_argmax(f32x2 f) {
    const float bv = wave_max_dpp(fmaxf(f.x, f.y));
    unsigned long long b0 = __ballot(f.x == bv);
    unsigned long long b1 = __ballot(f.y == bv);
    int i0 = __ffsll(b0);  // 1-based, 0 if none
    int i1 = __ffsll(b1);
    int c0 = i0 ? (i0 - 1) * 2 : (1 << 30);
    int c1 = i1 ? (i1 - 1) * 2 + 1 : (1 << 30);
    return min(c0, c1);
}

// 8-way dynamic register select (j is wave-uniform; 7 cndmask/cselect ops).
__device__ __forceinline__ unsigned sel8(const unsigned* t, int j) {
    unsigned a0 = (j & 1) ? t[1] : t[0];
    unsigned a1 = (j & 1) ? t[3] : t[2];
    unsigned a2 = (j & 1) ? t[5] : t[4];
    unsigned a3 = (j & 1) ? t[7] : t[6];
    unsigned b0 = (j & 2) ? a1 : a0;
    unsigned b1 = (j & 2) ? a3 : a2;
    return (j & 4) ? b1 : b0;
}

// Wave-uniform pointer -> value the compiler KNOWS is uniform (SGPR-allocatable).
__device__ __forceinline__ unsigned long long uniform_u64(const void* p) {
    unsigned long long x = (unsigned long long)p;
    unsigned lo = __builtin_amdgcn_readfirstlane((unsigned)x);
    unsigned hi = __builtin_amdgcn_readfirstlane((unsigned)(x >> 32));
    return ((unsigned long long)hi << 32) | lo;
}

// One fully-unrolled pipeline step. All indices compile-time; ring/fbuf live
// entirely in VGPRs (SROA: every access has a constant index).
template <int I>
struct Step {
    static __device__ __forceinline__ void run(f32x2* ring, f32x2* fbuf,
                                               const unsigned* tbl, int& prev,
                                               unsigned long long lbase,
                                               unsigned long long obase,
                                               unsigned laneoff) {
        // Exact count of vmem ops issued after this slot's load (issue order
        // per step: wait, store S_I, load L_{I+D}):
        //   prologue region (I<=D-1): D-1+I
        //   steady (I<=L-D-1):        2D-2
        //   tail (loads exhausted):   D-1+(L-1-I)
        constexpr int NW = (I <= D - 1) ? (D - 1 + I)
                         : ((I <= L - D - 1) ? (2 * D - 2) : (D - 1 + (L - 1 - I)));
        constexpr int s  = I % D;

        // Wait until row I's load retired. Ties:
        //  %0 ring[s]  -> consumers below are data-ordered after the wait
        //  %1 fbuf[s]  -> keeps the D-iter-old store's data reg alive until
        //                 this wait (which provably retires that store)
        asm volatile("s_waitcnt vmcnt(%c2)"
                     : "+v"(ring[s])
                     : "v"(fbuf[s]), "i"(NW));

        f32x2 c = ring[s];
        f32x2 f;
        if (I == 0) {
            f = c;  // row 0 passes through unfiltered
        } else {
            const unsigned word  = sel8(tbl, prev >> 4);
            const unsigned fbits = (word >> ((prev & 15) * 2)) & 3u;
            f.x = (fbits & 1u) ? c.x : 0.0f;
            f.y = (fbits & 2u) ? c.y : 0.0f;
        }
        fbuf[s] = f;

        {
            unsigned voff = (unsigned)I * ROWB + laneoff;
            // Plain store (acks at L2); `nt` forced HBM-path acks and cost ~8%.
            asm volatile("global_store_dwordx2 %0, %1, %2"
                         :
                         : "v"(voff), "v"(fbuf[s]), "s"(obase));
        }

        prev = wave_argmax(f);

        if constexpr (I + D < L) {
            unsigned voff = (unsigned)(I + D) * ROWB + laneoff;
            asm volatile("global_load_dwordx2 %0, %1, %2"
                         : "=&v"(ring[s])
                         : "v"(voff), "s"(lbase));
        }

        Step<I + 1>::run(ring, fbuf, tbl, prev, lbase, obase, laneoff);
    }
};
template <>
struct Step<L> {
    static __device__ __forceinline__ void run(f32x2*, f32x2*, const unsigned*,
                                               int&, unsigned long long,
                                               unsigned long long, unsigned) {}
};

__global__ __launch_bounds__(256, 4) void rule_filter_kernel(
    const float* __restrict__ logits,      // (L, N, V)
    const float* __restrict__ mask_table,  // (V, V)
    float* __restrict__ out)               // (L, N, V)
{
    const int wave = threadIdx.x >> 6;  // 0..3
    const int lane = threadIdx.x & 63;  // 0..63
    const int n    = (blockIdx.x << 2) + wave;

    // Wave-uniform base pointers, laundered to SGPR-provable uniformity.
    const unsigned long long lbase = uniform_u64(logits + (size_t)n * V);
    const unsigned long long obase = uniform_u64(out    + (size_t)n * V);
    const unsigned laneoff = (unsigned)lane * 8;  // dwordx2 per lane

    // Per-lane mask table: tbl[j] bits(2r..2r+1) = mask_table[16j+r][2l..2l+1]
    unsigned tbl[8];
#pragma unroll 1
    for (int j = 0; j < 8; ++j) {
        unsigned acc = 0;
#pragma unroll
        for (int r = 0; r < 16; ++r) {
            const int p = j * 16 + r;
            float2 mv = *(const float2*)(mask_table + (size_t)p * V + lane * 2);
            acc |= ((mv.x != 0.0f ? 1u : 0u) | (mv.y != 0.0f ? 2u : 0u)) << (2 * r);
        }
        tbl[j] = acc;
    }
    // Drain table loads so the hand-counted vmcnt ledger is exact.
    asm volatile("s_waitcnt vmcnt(0)" ::: "memory");

    f32x2 ring[D];
    f32x2 fbuf[D];
#pragma unroll
    for (int r = 0; r < D; ++r) { fbuf[r].x = 0.0f; fbuf[r].y = 0.0f; }

    // Prologue: issue loads for rows 0..D-1 (in order; vmcnt ops 1..D).
#pragma unroll
    for (int r = 0; r < D; ++r) {
        unsigned voff = (unsigned)r * ROWB + laneoff;
        asm volatile("global_load_dwordx2 %0, %1, %2"
                     : "=&v"(ring[r])
                     : "v"(voff), "s"(lbase));
    }

    int prev = 0;
    Step<0>::run(ring, fbuf, tbl, prev, lbase, obase, laneoff);
}

extern "C" void kernel_launch(void* const* d_in, const int* in_sizes, int n_in,
                              void* d_out, int out_size, void* d_ws, size_t ws_size,
                              hipStream_t stream) {
    const float* logits     = (const float*)d_in[0];  // (L, N, V) fp32
    const float* mask_table = (const float*)d_in[1];  // (V, V) fp32
    float* out              = (float*)d_out;          // (L, N, V) fp32

    dim3 grid(N / 4);  // 4 sequences (waves) per 256-thread block
    dim3 block(256);
    rule_filter_kernel<<<grid, block, 0, stream>>>(logits, mask_table, out);
}